// Round 3
// baseline (220.988 us; speedup 1.0000x reference)
//
#include <hip/hip_runtime.h>

#define T_STEPS 512
#define UNROLL 8
#define LOG2E 1.4426950408889634f

typedef float v2f __attribute__((ext_vector_type(2)));

// sigmoid via hw exp2 + rcp; tanh(x) = 2*sigmoid(2x) - 1 (handled by per-lane consts)
__device__ __forceinline__ float fsigmoid(float x) {
    float e = __builtin_amdgcn_exp2f(-LOG2E * x);
    return __builtin_amdgcn_rcpf(1.0f + e);
}

// DPP row rotate-right by R within the 16-lane row (~2-cycle cross-lane, no LDS)
template <int R>
__device__ __forceinline__ float rotf(float v) {
    const int i = __float_as_int(v);
    return __int_as_float(__builtin_amdgcn_update_dpp(i, i, 0x120 | R, 0xF, 0xF, false));
}

// 16 lanes per batch element. Lane l: j = l&7 (hidden unit), p = l>>3.
// p=0 owns gate rows {i:j, f:8+j}; p=1 owns {g:16+j, o:24+j}. Gate pair packed
// in float2 -> v_pk_fma_f32. h (dup across p) is all-gathered via DPP row_ror
// (row == the 16-lane group), W_hh pre-permuted per lane so rotation r pairs
// with unit m=(j-r)&7. Activation split (sigmoid vs tanh) is made uniform via
// tanh(x)=2*sigmoid(2x)-1 with per-lane constants; p0<->p1 exchange = row_ror:8.
__global__ __launch_bounds__(256) void lstm_kernel(
    const float* __restrict__ x, const float* __restrict__ W_ih,
    const float* __restrict__ W_hh, const float* __restrict__ b_ih,
    const float* __restrict__ b_hh, const float* __restrict__ W_fc,
    const float* __restrict__ b_fc, float* __restrict__ out, int B)
{
    const int tid = blockIdx.x * blockDim.x + threadIdx.x;
    const int b = tid >> 4;               // batch element
    if (b >= B) return;
    const int l = threadIdx.x & 15;       // position in 16-lane group (== DPP row)
    const int j = l & 7;                  // hidden unit
    const int p = l >> 3;                 // gate-pair half

    const int rA = p ? (16 + j) : j;        // g : i
    const int rB = p ? (24 + j) : (8 + j);  // o : f

    v2f wih[4], whh[8], bias;
    #pragma unroll
    for (int k = 0; k < 4; ++k)
        wih[k] = v2f{W_ih[rA * 4 + k], W_ih[rB * 4 + k]};
    #pragma unroll
    for (int r = 0; r < 8; ++r) {
        const int m = (j - r + 8) & 7;    // unit arriving at rotation r
        whh[r] = v2f{W_hh[rA * 8 + m], W_hh[rB * 8 + m]};
    }
    bias = v2f{b_ih[rA] + b_hh[rA], b_ih[rB] + b_hh[rB]};

    // actA = sA * sigmoid(preA * aA) + oA :  p0 -> sigmoid(i), p1 -> tanh(g)
    const float preA = p ? 2.0f : 1.0f;
    const float sA   = p ? 2.0f : 1.0f;
    const float oA   = p ? -1.0f : 0.0f;

    const float4* xb = (const float4*)(x + (size_t)b * (T_STEPS * 4));
    float4 cur[UNROLL], nxt[UNROLL];
    #pragma unroll
    for (int k = 0; k < UNROLL; ++k) cur[k] = xb[k];

    float c = 0.0f, h = 0.0f;

    for (int base = 0; base < T_STEPS; base += UNROLL) {
        const int nbase = (base + UNROLL < T_STEPS) ? base + UNROLL : 0;
        #pragma unroll
        for (int k = 0; k < UNROLL; ++k) nxt[k] = xb[nbase + k];

        #pragma unroll
        for (int k = 0; k < UNROLL; ++k) {
            const float4 xt = cur[k];

            // two packed accumulators (tree) -> shorter dep chain
            v2f a0 = bias, a1 = v2f{0.0f, 0.0f};
            a0 += xt.x * wih[0]; a1 += xt.y * wih[1];
            a0 += xt.z * wih[2]; a1 += xt.w * wih[3];
            a0 += h * whh[0];
            a1 += rotf<1>(h) * whh[1];
            a0 += rotf<2>(h) * whh[2];
            a1 += rotf<3>(h) * whh[3];
            a0 += rotf<4>(h) * whh[4];
            a1 += rotf<5>(h) * whh[5];
            a0 += rotf<6>(h) * whh[6];
            a1 += rotf<7>(h) * whh[7];
            const v2f a = a0 + a1;

            const float u   = fsigmoid(preA * a.x);
            const float actA = fmaf(u, sA, oA);    // p0: sig(i), p1: tanh(g)
            const float actB = fsigmoid(a.y);      // p0: sig(f), p1: sig(o)

            const float rAv = rotf<8>(actA);       // partner's actA
            const float rBv = rotf<8>(actB);       // partner's actB

            const float i_ = p ? rAv  : actA;
            const float f_ = p ? rBv  : actB;
            const float g_ = p ? actA : rAv;
            const float o_ = p ? actB : rBv;

            c = fmaf(f_, c, i_ * g_);
            const float tc = fmaf(fsigmoid(2.0f * c), 2.0f, -1.0f);  // tanh(c)
            h = o_ * tc;
        }

        #pragma unroll
        for (int k = 0; k < UNROLL; ++k) cur[k] = nxt[k];
    }

    // out[b] = h . W_fc + b_fc  (both 8-lane halves hold identical h sets)
    float pr = h * W_fc[j];
    pr += __shfl_xor(pr, 1);
    pr += __shfl_xor(pr, 2);
    pr += __shfl_xor(pr, 4);
    if (l == 0) out[b] = pr + b_fc[0];
}

extern "C" void kernel_launch(void* const* d_in, const int* in_sizes, int n_in,
                              void* d_out, int out_size, void* d_ws, size_t ws_size,
                              hipStream_t stream) {
    const float* x    = (const float*)d_in[0];
    const float* W_ih = (const float*)d_in[1];
    const float* W_hh = (const float*)d_in[2];
    const float* b_ih = (const float*)d_in[3];
    const float* b_hh = (const float*)d_in[4];
    const float* W_fc = (const float*)d_in[5];
    const float* b_fc = (const float*)d_in[6];
    float* out = (float*)d_out;

    const int B = in_sizes[0] / (T_STEPS * 4);   // 8192
    const int threads = B * 16;
    const int block = 256;
    const int grid = (threads + block - 1) / block;
    lstm_kernel<<<grid, block, 0, stream>>>(x, W_ih, W_hh, b_ih, b_hh, W_fc, b_fc, out, B);
}